// Round 1
// 151.059 us; speedup vs baseline: 1.0289x; 1.0289x over previous
//
#include <hip/hip_runtime.h>
#include <hip/hip_fp16.h>

#define HID 2048
#define FIVEH 10240
#define INP 128
#define BATCH 2048

typedef _Float16 half8 __attribute__((ext_vector_type(8)));
typedef float f32x4 __attribute__((ext_vector_type(4)));

// load 8 consecutive f32, convert to half8 in-register
__device__ __forceinline__ half8 cvt8(const float* p) {
  float4 a = *(const float4*)p;
  float4 b = *(const float4*)(p + 4);
  half8 h;
  h[0] = (_Float16)a.x; h[1] = (_Float16)a.y; h[2] = (_Float16)a.z; h[3] = (_Float16)a.w;
  h[4] = (_Float16)b.x; h[5] = (_Float16)b.y; h[6] = (_Float16)b.z; h[7] = (_Float16)b.w;
  return h;
}

// ---------------- GEMM v3 (unchanged, verified): LDS-staged W, transposed epilogue ----
#define WSTRIDE 136
__global__ __launch_bounds__(256) void gemm_up(const float* __restrict__ A,
                                               const float* __restrict__ W,
                                               const float* __restrict__ bias,
                                               _Float16* __restrict__ up16,
                                               int row0, int nrows) {
  __shared__ _Float16 Ws[128 * WSTRIDE];
  int tid = threadIdx.x, wave = tid >> 6, lane = tid & 63;
  int bx = blockIdx.x;
  int by = blockIdx.y;
  int nl = lane & 15, quad = lane >> 4;

  {
    const float* src = W + (size_t)(bx * 128) * INP;
#pragma unroll
    for (int it = 0; it < 8; ++it) {
      int n = (it * 256 + tid) * 8;
      int col = n >> 7, k = n & 127;
      *(half8*)(Ws + col * WSTRIDE + k) = cvt8(src + n);
    }
  }

  half8 af[2][4];
  int rowbase = row0 + by * 128 + wave * 32;
#pragma unroll
  for (int mt = 0; mt < 2; ++mt) {
    const float* ar = A + (size_t)(rowbase + mt * 16 + nl) * INP + quad * 8;
#pragma unroll
    for (int ks = 0; ks < 4; ++ks) af[mt][ks] = cvt8(ar + ks * 32);
  }
  __syncthreads();

  f32x4 acc[2][8];
#pragma unroll
  for (int nt = 0; nt < 8; ++nt) {
    half8 bf[4];
#pragma unroll
    for (int ks = 0; ks < 4; ++ks)
      bf[ks] = *(const half8*)(Ws + (nt * 16 + nl) * WSTRIDE + quad * 8 + ks * 32);
#pragma unroll
    for (int mt = 0; mt < 2; ++mt) {
      f32x4 a = {0.f, 0.f, 0.f, 0.f};
#pragma unroll
      for (int ks = 0; ks < 4; ++ks)
        a = __builtin_amdgcn_mfma_f32_16x16x32_f16(af[mt][ks], bf[ks], a, 0, 0, 0);
      acc[mt][nt] = a;
    }
  }
  __syncthreads();

#pragma unroll
  for (int nt = 0; nt < 8; ++nt) {
    float bv = bias[bx * 128 + nt * 16 + nl];
#pragma unroll
    for (int mt = 0; mt < 2; ++mt) {
      int rl = wave * 32 + mt * 16 + quad * 4;
#pragma unroll
      for (int r = 0; r < 4; ++r)
        Ws[(rl + r) * WSTRIDE + nt * 16 + nl] = (_Float16)(acc[mt][nt][r] + bv);
    }
  }
  __syncthreads();

#pragma unroll
  for (int it = 0; it < 8; ++it) {
    int v = it * 256 + tid;
    int r = v >> 4, c8 = (v & 15) * 8;
    *(half8*)(up16 + (size_t)(by * 128 + r) * FIVEH + bx * 128 + c8) =
        *(const half8*)(Ws + r * WSTRIDE + c8);
  }
}

// ---------------- f16-LDS helpers ----------------
__device__ __forceinline__ float2 h2ld(const __half2* p, int i) {
  return __half22float2(p[i]);
}
__device__ __forceinline__ void h2st(__half2* p, int i, float x, float y) {
  p[i] = __floats2half2_rn(x, y);
}

// ---------------- fused FFT pieces (same Stockham math as verified fft_r4) ----------
// HEAD: radix-2 (stride 1024) + radix-4 L=2, entirely in registers.
// Input: v[e] = point (tid + 256e). Output: the exact words the original pass-0 wrote,
// which for this thread are the 8 CONTIGUOUS LDS words [8*tid .. 8*tid+7] (2x b128).
// L=2 twiddles are compile-time constants (k=0 -> 1; k=1 -> w, w^2, w^3 with w=e^{sgn i pi/4}).
__device__ __forceinline__ void fft_head(const float2 v[8], __half2* dst, int tid, float sgn) {
  const float R2 = 0.70710678118654752f;
  float2 o[8];
  {  // i' = 2*tid : x_j = v[j] + v[j+4], k=0 (unit twiddles)
    float x0r = v[0].x + v[4].x, x0i = v[0].y + v[4].y;
    float x1r = v[1].x + v[5].x, x1i = v[1].y + v[5].y;
    float x2r = v[2].x + v[6].x, x2i = v[2].y + v[6].y;
    float x3r = v[3].x + v[7].x, x3i = v[3].y + v[7].y;
    float t0r = x0r + x2r, t0i = x0i + x2i, t1r = x0r - x2r, t1i = x0i - x2i;
    float t2r = x1r + x3r, t2i = x1i + x3i, t3r = x1r - x3r, t3i = x1i - x3i;
    o[0].x = t0r + t2r;       o[0].y = t0i + t2i;
    o[4].x = t0r - t2r;       o[4].y = t0i - t2i;
    o[2].x = t1r - sgn * t3i; o[2].y = t1i + sgn * t3r;
    o[6].x = t1r + sgn * t3i; o[6].y = t1i - sgn * t3r;
  }
  {  // i' = 2*tid+1 : x_j = v[j] - v[j+4], k=1 -> c1=R2,s1=sgn*R2; c2=0,s2=sgn; c3=-R2,s3=sgn*R2
    float x0r = v[0].x - v[4].x, x0i = v[0].y - v[4].y;
    float x1r = v[1].x - v[5].x, x1i = v[1].y - v[5].y;
    float x2r = v[2].x - v[6].x, x2i = v[2].y - v[6].y;
    float x3r = v[3].x - v[7].x, x3i = v[3].y - v[7].y;
    float y1r = (x1r - sgn * x1i) * R2,  y1i = (sgn * x1r + x1i) * R2;
    float y2r = -sgn * x2i,              y2i = sgn * x2r;
    float y3r = -(x3r + sgn * x3i) * R2, y3i = (sgn * x3r - x3i) * R2;
    float t0r = x0r + y2r, t0i = x0i + y2i, t1r = x0r - y2r, t1i = x0i - y2i;
    float t2r = y1r + y3r, t2i = y1i + y3i, t3r = y1r - y3r, t3i = y1i - y3i;
    o[1].x = t0r + t2r;       o[1].y = t0i + t2i;
    o[5].x = t0r - t2r;       o[5].y = t0i - t2i;
    o[3].x = t1r - sgn * t3i; o[3].y = t1i + sgn * t3r;
    o[7].x = t1r + sgn * t3i; o[7].y = t1i - sgn * t3r;
  }
  __half2* base = dst + 8 * tid;  // 32B-aligned, contiguous -> b128 writes, conflict-free
#pragma unroll
  for (int j = 0; j < 8; ++j) h2st(base, j, o[j].x, o[j].y);
}

// MID: one radix-4 LDS pass, L in {8,32,128}. 256 % L == 0 so k (and the twiddle
// sincos) is identical for both t iterations -> computed ONCE (was 2x).
template <int L>
__device__ __forceinline__ void fft_mid(const __half2* __restrict__ src,
                                        __half2* __restrict__ dst, int tid, float sgn) {
  static_assert(256 % L == 0, "twiddle hoist requires 256 % L == 0");
  const int k = tid & (L - 1);
  float s1, c1;
  __sincosf(sgn * (1.5707963267948966f / (float)L) * (float)k, &s1, &c1);
  float c2 = c1 * c1 - s1 * s1, s2 = 2.f * c1 * s1;
  float c3 = c1 * c2 - s1 * s2, s3 = c1 * s2 + s1 * c2;
#pragma unroll
  for (int t = 0; t < 2; ++t) {
    int i = tid + (t << 8);
    int base4 = ((i - k) << 2) + k;
    float2 x0 = h2ld(src, i),        x1 = h2ld(src, i + 512);
    float2 x2 = h2ld(src, i + 1024), x3 = h2ld(src, i + 1536);
    float y1r = x1.x * c1 - x1.y * s1, y1i = x1.x * s1 + x1.y * c1;
    float y2r = x2.x * c2 - x2.y * s2, y2i = x2.x * s2 + x2.y * c2;
    float y3r = x3.x * c3 - x3.y * s3, y3i = x3.x * s3 + x3.y * c3;
    float t0r = x0.x + y2r, t0i = x0.y + y2i;
    float t1r = x0.x - y2r, t1i = x0.y - y2i;
    float t2r = y1r + y3r, t2i = y1i + y3i;
    float t3r = y1r - y3r, t3i = y1i - y3i;
    h2st(dst, base4,         t0r + t2r, t0i + t2i);
    h2st(dst, base4 + 2 * L, t0r - t2r, t0i - t2i);
    h2st(dst, base4 + L,     t1r - sgn * t3i, t1i + sgn * t3r);
    h2st(dst, base4 + 3 * L, t1r + sgn * t3i, t1i - sgn * t3r);
  }
}

// TAIL: final radix-4 pass (L=512) straight into registers. This pass writes exactly
// points (tid + 256e): t=0 -> e{0,2,4,6}, t=1 -> e{1,3,5,7}. Keeps f32 precision for
// the Householder steps and deletes a full LDS write+read round.
__device__ __forceinline__ void fft_tail(const __half2* __restrict__ src, float2 h[8],
                                         int tid, float sgn) {
#pragma unroll
  for (int t = 0; t < 2; ++t) {
    int i = tid + (t << 8);  // i in [0,512), k = i, base4 = i
    float s1, c1;
    __sincosf(sgn * (1.5707963267948966f / 512.f) * (float)i, &s1, &c1);
    float c2 = c1 * c1 - s1 * s1, s2 = 2.f * c1 * s1;
    float c3 = c1 * c2 - s1 * s2, s3 = c1 * s2 + s1 * c2;
    float2 x0 = h2ld(src, i),        x1 = h2ld(src, i + 512);
    float2 x2 = h2ld(src, i + 1024), x3 = h2ld(src, i + 1536);
    float y1r = x1.x * c1 - x1.y * s1, y1i = x1.x * s1 + x1.y * c1;
    float y2r = x2.x * c2 - x2.y * s2, y2i = x2.x * s2 + x2.y * c2;
    float y3r = x3.x * c3 - x3.y * s3, y3i = x3.x * s3 + x3.y * c3;
    float t0r = x0.x + y2r, t0i = x0.y + y2i;
    float t1r = x0.x - y2r, t1i = x0.y - y2i;
    float t2r = y1r + y3r, t2i = y1i + y3i;
    float t3r = y1r - y3r, t3i = y1i - y3i;
    h[t].x     = t0r + t2r;       h[t].y     = t0i + t2i;
    h[t + 4].x = t0r - t2r;       h[t + 4].y = t0i - t2i;
    h[t + 2].x = t1r - sgn * t3i; h[t + 2].y = t1i + sgn * t3r;
    h[t + 6].x = t1r + sgn * t3i; h[t + 6].y = t1i - sgn * t3r;
  }
}

// wave shfl reduce + tiny LDS combine
__device__ __forceinline__ void block_reduce2(float& pr, float& pi,
                                              float* redr, float* redi, int tid) {
  for (int off = 32; off > 0; off >>= 1) {
    pr += __shfl_down(pr, off, 64);
    pi += __shfl_down(pi, off, 64);
  }
  if ((tid & 63) == 0) { redr[tid >> 6] = pr; redi[tid >> 6] = pi; }
  __syncthreads();
  pr = redr[0] + redr[1] + redr[2] + redr[3];
  pi = redi[0] + redi[1] + redi[2] + redi[3];
  __syncthreads();
}

// omode: 0 interleaved, 1 planar, 2 real-only. invN folded at the permute step.
// Pipeline (13 barriers, 9R+9W LDS rounds; was 21 / 15R+15W):
//   regs{d1*hx, r2, L=2} -> sA | mid8 sA->sB | mid32 sB->sA | mid128 sA->sB |
//   tail sB->regs | hh1 in regs (reduce) | regs -> sA | gather sA + d2/invN ->
//   regs{r2, L=2} -> sB | mid8 sB->sA | mid32 sA->sB | mid128 sB->sA |
//   tail sA->regs | hh2 + d3 + modrelu in regs -> out
#define ROW_PIPELINE(UP)                                                        \
  float2 hreg[8];                                                               \
  {                                                                             \
    float2 v[8];                                                                \
    _Pragma("unroll") for (int e = 0; e < 8; ++e) {                             \
      int k = tid + (e << 8);                                                   \
      float sv, cv; __sincosf(UP(e, 0), &sv, &cv);                              \
      float hr = hxr[(size_t)b * HID + k];                                      \
      float hi = hxi[(size_t)b * HID + k];                                      \
      v[e].x = cv * hr - sv * hi; v[e].y = cv * hi + sv * hr;                   \
    }                                                                           \
    fft_head(v, sA, tid, -1.f);                                                 \
  }                                                                             \
  __syncthreads();                                                              \
  fft_mid<8>(sA, sB, tid, -1.f);   __syncthreads();                             \
  fft_mid<32>(sB, sA, tid, -1.f);  __syncthreads();                             \
  fft_mid<128>(sA, sB, tid, -1.f); __syncthreads();                             \
  fft_tail(sB, hreg, tid, -1.f);                                                \
  float cc[8], ss[8];                                                           \
  {                                                                             \
    float pr = 0.f, pi = 0.f;                                                   \
    _Pragma("unroll") for (int e = 0; e < 8; ++e) {                             \
      float sv, cv; __sincosf(UP(e, 3), &sv, &cv);                              \
      cc[e] = cv; ss[e] = sv;                                                   \
      pr += cv * hreg[e].x + sv * hreg[e].y;                                    \
      pi += cv * hreg[e].y - sv * hreg[e].x;                                    \
    }                                                                           \
    block_reduce2(pr, pi, redr, redi, tid);                                     \
    _Pragma("unroll") for (int e = 0; e < 8; ++e) {                             \
      int k = tid + (e << 8);                                                   \
      h2st(sA, k, hreg[e].x - 2.f * (cc[e] * pr - ss[e] * pi),                  \
                  hreg[e].y - 2.f * (cc[e] * pi + ss[e] * pr));                 \
    }                                                                           \
  }                                                                             \
  __syncthreads();                                                              \
  {                                                                             \
    const float invN = 1.0f / (float)HID;                                       \
    float2 v[8];                                                                \
    _Pragma("unroll") for (int e = 0; e < 8; ++e) {                             \
      int k = tid + (e << 8);                                                   \
      float sv, cv; __sincosf(UP(e, 1), &sv, &cv);                              \
      float2 hh = h2ld(sA, perm[k]);                                            \
      v[e].x = (cv * hh.x - sv * hh.y) * invN;                                  \
      v[e].y = (cv * hh.y + sv * hh.x) * invN;                                  \
    }                                                                           \
    fft_head(v, sB, tid, 1.f);                                                  \
  }                                                                             \
  __syncthreads();                                                              \
  fft_mid<8>(sB, sA, tid, 1.f);   __syncthreads();                              \
  fft_mid<32>(sA, sB, tid, 1.f);  __syncthreads();                              \
  fft_mid<128>(sB, sA, tid, 1.f); __syncthreads();                              \
  fft_tail(sA, hreg, tid, 1.f);                                                 \
  float prj_r, prj_i;                                                           \
  {                                                                             \
    float pr = 0.f, pi = 0.f;                                                   \
    _Pragma("unroll") for (int e = 0; e < 8; ++e) {                             \
      float sv, cv; __sincosf(UP(e, 4), &sv, &cv);                              \
      cc[e] = cv; ss[e] = sv;                                                   \
      pr += cv * hreg[e].x + sv * hreg[e].y;                                    \
      pi += cv * hreg[e].y - sv * hreg[e].x;                                    \
    }                                                                           \
    block_reduce2(pr, pi, redr, redi, tid);                                     \
    prj_r = pr; prj_i = pi;                                                     \
  }                                                                             \
  _Pragma("unroll") for (int e = 0; e < 8; ++e) {                               \
    int k = tid + (e << 8);                                                     \
    float hr = hreg[e].x - 2.f * (cc[e] * prj_r - ss[e] * prj_i);               \
    float hi = hreg[e].y - 2.f * (cc[e] * prj_i + ss[e] * prj_r);               \
    float s3, c3; __sincosf(UP(e, 2), &s3, &c3);                                \
    float zr = c3 * hr - s3 * hi;                                               \
    float zi = c3 * hi + s3 * hr;                                               \
    float mag = sqrtf(zr * zr + zi * zi);                                       \
    float nm = mag + beta[k];                                                   \
    nm = nm > 0.f ? nm : 0.f;                                                   \
    float orr, oii;                                                             \
    if (mag > 0.f) { float sc = nm / mag; orr = zr * sc; oii = zi * sc; }       \
    else { orr = nm; oii = 0.f; }                                               \
    long m = (long)b * HID + k;                                                 \
    if (omode == 1) {                                                           \
      const long half = (long)BATCH * HID;                                      \
      if (half + m < out_size_l) { out[m] = orr; out[half + m] = oii; }         \
    } else if (omode == 0) {                                                    \
      if (2 * m + 1 < out_size_l) {                                             \
        float2 o; o.x = orr; o.y = oii;                                         \
        *(float2*)(out + 2 * m) = o;                                            \
      }                                                                         \
    } else {                                                                    \
      if (m < out_size_l) out[m] = orr;                                         \
    }                                                                           \
  }

// ---------------- row kernel: f16 LDS ping-pong, register-fused head/tail ----------
__global__ __launch_bounds__(256, 8) void urnn_row(const _Float16* __restrict__ up16,
                                                   const float* __restrict__ hxr,
                                                   const float* __restrict__ hxi,
                                                   const float* __restrict__ beta,
                                                   const int* __restrict__ perm,
                                                   float* __restrict__ out,
                                                   int row0, long out_size_l, int omode) {
  __shared__ __half2 sA[HID], sB[HID];
  __shared__ float redr[4], redi[4];

  int tid = threadIdx.x;
  int b = row0 + blockIdx.x;
  const _Float16* uprow = up16 + (size_t)blockIdx.x * FIVEH;
#define UPG(e, s) ((float)uprow[(s) * HID + tid + ((e) << 8)])
  ROW_PIPELINE(UPG)
#undef UPG
}

// ---------------- ws-free fused fallback (f32-exact per-thread GEMM) ------------------
__global__ __launch_bounds__(256) void urnn_fused(const float* __restrict__ A,
                                                  const float* __restrict__ W,
                                                  const float* __restrict__ bias,
                                                  const float* __restrict__ hxr,
                                                  const float* __restrict__ hxi,
                                                  const float* __restrict__ beta,
                                                  const int* __restrict__ perm,
                                                  float* __restrict__ out,
                                                  long out_size_l, int omode) {
  __shared__ __half2 sA[HID], sB[HID];
  __shared__ float redr[4], redi[4];
  __shared__ float4 xs4[INP / 4];

  int tid = threadIdx.x;
  int b = blockIdx.x;

  if (tid < INP / 4) xs4[tid] = ((const float4*)(A + (size_t)b * INP))[tid];
  __syncthreads();

  float upreg[40];
#pragma unroll
  for (int se = 0; se < 40; ++se) {
    int n = ((se >> 3) << 11) + ((se & 7) << 8) + tid;
    upreg[se] = bias[n];
  }
  for (int kb = 0; kb < 4; ++kb) {
    float4 xv[8];
#pragma unroll
    for (int j = 0; j < 8; ++j) xv[j] = xs4[kb * 8 + j];
#pragma unroll
    for (int se = 0; se < 40; ++se) {
      int n = ((se >> 3) << 11) + ((se & 7) << 8) + tid;
      const float4* wr = (const float4*)(W + (size_t)n * INP + (kb << 5));
      float a = 0.f;
#pragma unroll
      for (int j = 0; j < 8; ++j) {
        float4 wv = wr[j];
        a += xv[j].x * wv.x + xv[j].y * wv.y + xv[j].z * wv.z + xv[j].w * wv.w;
      }
      upreg[se] += a;
    }
  }
#define UPR(e, s) (upreg[(s) * 8 + (e)])
  ROW_PIPELINE(UPR)
#undef UPR
}

extern "C" void kernel_launch(void* const* d_in, const int* in_sizes, int n_in,
                              void* d_out, int out_size, void* d_ws, size_t ws_size,
                              hipStream_t stream) {
  const float* input   = (const float*)d_in[0];
  const float* hx_real = (const float*)d_in[1];
  const float* hx_imag = (const float*)d_in[2];
  const float* W       = (const float*)d_in[3];
  const float* bvec    = (const float*)d_in[4];
  const float* beta    = (const float*)d_in[5];
  const int*   perm    = (const int*)d_in[6];

  int omode;
  if (out_size == BATCH * HID) omode = 2;
  else if (out_size == 2 * BATCH * HID) omode = 1;
  else omode = 0;

  const size_t rowbytes = (size_t)FIVEH * sizeof(_Float16);
  long chunk = (long)(ws_size / rowbytes);
  if (chunk > BATCH) chunk = BATCH;
  chunk &= ~127L;

  if (chunk >= 128) {
    _Float16* up16 = (_Float16*)d_ws;
    for (long row0 = 0; row0 < BATCH; row0 += chunk) {
      int rows = (int)((row0 + chunk <= BATCH) ? chunk : (BATCH - row0));
      dim3 g(FIVEH / 128, rows / 128);
      gemm_up<<<g, 256, 0, stream>>>(input, W, bvec, up16, (int)row0, rows);
      urnn_row<<<rows, 256, 0, stream>>>(up16, hx_real, hx_imag, beta, perm,
                                         (float*)d_out, (int)row0, (long)out_size, omode);
    }
  } else {
    urnn_fused<<<BATCH, 256, 0, stream>>>(input, W, bvec, hx_real, hx_imag, beta, perm,
                                          (float*)d_out, (long)out_size, omode);
  }
}

// Round 2
// 144.405 us; speedup vs baseline: 1.0763x; 1.0461x over previous
//
#include <hip/hip_runtime.h>
#include <hip/hip_fp16.h>

#define HID 2048
#define FIVEH 10240
#define INP 128
#define BATCH 2048

typedef _Float16 half8 __attribute__((ext_vector_type(8)));
typedef float f32x4 __attribute__((ext_vector_type(4)));

// load 8 consecutive f32, convert to half8 in-register
__device__ __forceinline__ half8 cvt8(const float* p) {
  float4 a = *(const float4*)p;
  float4 b = *(const float4*)(p + 4);
  half8 h;
  h[0] = (_Float16)a.x; h[1] = (_Float16)a.y; h[2] = (_Float16)a.z; h[3] = (_Float16)a.w;
  h[4] = (_Float16)b.x; h[5] = (_Float16)b.y; h[6] = (_Float16)b.z; h[7] = (_Float16)b.w;
  return h;
}

// ---------------- GEMM v3 (unchanged, verified): LDS-staged W, transposed epilogue ----
#define WSTRIDE 136
__global__ __launch_bounds__(256) void gemm_up(const float* __restrict__ A,
                                               const float* __restrict__ W,
                                               const float* __restrict__ bias,
                                               _Float16* __restrict__ up16,
                                               int row0, int nrows) {
  __shared__ _Float16 Ws[128 * WSTRIDE];
  int tid = threadIdx.x, wave = tid >> 6, lane = tid & 63;
  int bx = blockIdx.x;
  int by = blockIdx.y;
  int nl = lane & 15, quad = lane >> 4;

  {
    const float* src = W + (size_t)(bx * 128) * INP;
#pragma unroll
    for (int it = 0; it < 8; ++it) {
      int n = (it * 256 + tid) * 8;
      int col = n >> 7, k = n & 127;
      *(half8*)(Ws + col * WSTRIDE + k) = cvt8(src + n);
    }
  }

  half8 af[2][4];
  int rowbase = row0 + by * 128 + wave * 32;
#pragma unroll
  for (int mt = 0; mt < 2; ++mt) {
    const float* ar = A + (size_t)(rowbase + mt * 16 + nl) * INP + quad * 8;
#pragma unroll
    for (int ks = 0; ks < 4; ++ks) af[mt][ks] = cvt8(ar + ks * 32);
  }
  __syncthreads();

  f32x4 acc[2][8];
#pragma unroll
  for (int nt = 0; nt < 8; ++nt) {
    half8 bf[4];
#pragma unroll
    for (int ks = 0; ks < 4; ++ks)
      bf[ks] = *(const half8*)(Ws + (nt * 16 + nl) * WSTRIDE + quad * 8 + ks * 32);
#pragma unroll
    for (int mt = 0; mt < 2; ++mt) {
      f32x4 a = {0.f, 0.f, 0.f, 0.f};
#pragma unroll
      for (int ks = 0; ks < 4; ++ks)
        a = __builtin_amdgcn_mfma_f32_16x16x32_f16(af[mt][ks], bf[ks], a, 0, 0, 0);
      acc[mt][nt] = a;
    }
  }
  __syncthreads();

#pragma unroll
  for (int nt = 0; nt < 8; ++nt) {
    float bv = bias[bx * 128 + nt * 16 + nl];
#pragma unroll
    for (int mt = 0; mt < 2; ++mt) {
      int rl = wave * 32 + mt * 16 + quad * 4;
#pragma unroll
      for (int r = 0; r < 4; ++r)
        Ws[(rl + r) * WSTRIDE + nt * 16 + nl] = (_Float16)(acc[mt][nt][r] + bv);
    }
  }
  __syncthreads();

#pragma unroll
  for (int it = 0; it < 8; ++it) {
    int v = it * 256 + tid;
    int r = v >> 4, c8 = (v & 15) * 8;
    *(half8*)(up16 + (size_t)(by * 128 + r) * FIVEH + bx * 128 + c8) =
        *(const half8*)(Ws + r * WSTRIDE + c8);
  }
}

// ---------------- f16-LDS helpers ----------------
__device__ __forceinline__ float2 h2ld(const __half2* p, int i) {
  return __half22float2(p[i]);
}
__device__ __forceinline__ void h2st(__half2* p, int i, float x, float y) {
  p[i] = __floats2half2_rn(x, y);
}

// ---------------- fused FFT pieces (same Stockham math as verified fft_r4) ----------
// HEAD: radix-2 (stride 1024) + radix-4 L=2, entirely in registers.
__device__ __forceinline__ void fft_head(const float2 v[8], __half2* dst, int tid, float sgn) {
  const float R2 = 0.70710678118654752f;
  float2 o[8];
  {  // i' = 2*tid : x_j = v[j] + v[j+4], k=0 (unit twiddles)
    float x0r = v[0].x + v[4].x, x0i = v[0].y + v[4].y;
    float x1r = v[1].x + v[5].x, x1i = v[1].y + v[5].y;
    float x2r = v[2].x + v[6].x, x2i = v[2].y + v[6].y;
    float x3r = v[3].x + v[7].x, x3i = v[3].y + v[7].y;
    float t0r = x0r + x2r, t0i = x0i + x2i, t1r = x0r - x2r, t1i = x0i - x2i;
    float t2r = x1r + x3r, t2i = x1i + x3i, t3r = x1r - x3r, t3i = x1i - x3i;
    o[0].x = t0r + t2r;       o[0].y = t0i + t2i;
    o[4].x = t0r - t2r;       o[4].y = t0i - t2i;
    o[2].x = t1r - sgn * t3i; o[2].y = t1i + sgn * t3r;
    o[6].x = t1r + sgn * t3i; o[6].y = t1i - sgn * t3r;
  }
  {  // i' = 2*tid+1 : x_j = v[j] - v[j+4], k=1 -> c1=R2,s1=sgn*R2; c2=0,s2=sgn; c3=-R2,s3=sgn*R2
    float x0r = v[0].x - v[4].x, x0i = v[0].y - v[4].y;
    float x1r = v[1].x - v[5].x, x1i = v[1].y - v[5].y;
    float x2r = v[2].x - v[6].x, x2i = v[2].y - v[6].y;
    float x3r = v[3].x - v[7].x, x3i = v[3].y - v[7].y;
    float y1r = (x1r - sgn * x1i) * R2,  y1i = (sgn * x1r + x1i) * R2;
    float y2r = -sgn * x2i,              y2i = sgn * x2r;
    float y3r = -(x3r + sgn * x3i) * R2, y3i = (sgn * x3r - x3i) * R2;
    float t0r = x0r + y2r, t0i = x0i + y2i, t1r = x0r - y2r, t1i = x0i - y2i;
    float t2r = y1r + y3r, t2i = y1i + y3i, t3r = y1r - y3r, t3i = y1i - y3i;
    o[1].x = t0r + t2r;       o[1].y = t0i + t2i;
    o[5].x = t0r - t2r;       o[5].y = t0i - t2i;
    o[3].x = t1r - sgn * t3i; o[3].y = t1i + sgn * t3r;
    o[7].x = t1r + sgn * t3i; o[7].y = t1i - sgn * t3r;
  }
  __half2* base = dst + 8 * tid;  // contiguous 32B -> merged b128 writes
#pragma unroll
  for (int j = 0; j < 8; ++j) h2st(base, j, o[j].x, o[j].y);
}

// MID: one radix-4 LDS pass, L in {8,32,128}; twiddle sincos hoisted (256 % L == 0).
template <int L>
__device__ __forceinline__ void fft_mid(const __half2* __restrict__ src,
                                        __half2* __restrict__ dst, int tid, float sgn) {
  static_assert(256 % L == 0, "twiddle hoist requires 256 % L == 0");
  const int k = tid & (L - 1);
  float s1, c1;
  __sincosf(sgn * (1.5707963267948966f / (float)L) * (float)k, &s1, &c1);
  float c2 = c1 * c1 - s1 * s1, s2 = 2.f * c1 * s1;
  float c3 = c1 * c2 - s1 * s2, s3 = c1 * s2 + s1 * c2;
#pragma unroll
  for (int t = 0; t < 2; ++t) {
    int i = tid + (t << 8);
    int base4 = ((i - k) << 2) + k;
    float2 x0 = h2ld(src, i),        x1 = h2ld(src, i + 512);
    float2 x2 = h2ld(src, i + 1024), x3 = h2ld(src, i + 1536);
    float y1r = x1.x * c1 - x1.y * s1, y1i = x1.x * s1 + x1.y * c1;
    float y2r = x2.x * c2 - x2.y * s2, y2i = x2.x * s2 + x2.y * c2;
    float y3r = x3.x * c3 - x3.y * s3, y3i = x3.x * s3 + x3.y * c3;
    float t0r = x0.x + y2r, t0i = x0.y + y2i;
    float t1r = x0.x - y2r, t1i = x0.y - y2i;
    float t2r = y1r + y3r, t2i = y1i + y3i;
    float t3r = y1r - y3r, t3i = y1i - y3i;
    h2st(dst, base4,         t0r + t2r, t0i + t2i);
    h2st(dst, base4 + 2 * L, t0r - t2r, t0i - t2i);
    h2st(dst, base4 + L,     t1r - sgn * t3i, t1i + sgn * t3r);
    h2st(dst, base4 + 3 * L, t1r + sgn * t3i, t1i - sgn * t3r);
  }
}

// TAIL: final radix-4 pass (L=512) straight into registers (points tid+256e).
__device__ __forceinline__ void fft_tail(const __half2* __restrict__ src, float2 h[8],
                                         int tid, float sgn) {
#pragma unroll
  for (int t = 0; t < 2; ++t) {
    int i = tid + (t << 8);  // i in [0,512), k = i, base4 = i
    float s1, c1;
    __sincosf(sgn * (1.5707963267948966f / 512.f) * (float)i, &s1, &c1);
    float c2 = c1 * c1 - s1 * s1, s2 = 2.f * c1 * s1;
    float c3 = c1 * c2 - s1 * s2, s3 = c1 * s2 + s1 * c2;
    float2 x0 = h2ld(src, i),        x1 = h2ld(src, i + 512);
    float2 x2 = h2ld(src, i + 1024), x3 = h2ld(src, i + 1536);
    float y1r = x1.x * c1 - x1.y * s1, y1i = x1.x * s1 + x1.y * c1;
    float y2r = x2.x * c2 - x2.y * s2, y2i = x2.x * s2 + x2.y * c2;
    float y3r = x3.x * c3 - x3.y * s3, y3i = x3.x * s3 + x3.y * c3;
    float t0r = x0.x + y2r, t0i = x0.y + y2i;
    float t1r = x0.x - y2r, t1i = x0.y - y2i;
    float t2r = y1r + y3r, t2i = y1i + y3i;
    float t3r = y1r - y3r, t3i = y1i - y3i;
    h[t].x     = t0r + t2r;       h[t].y     = t0i + t2i;
    h[t + 4].x = t0r - t2r;       h[t + 4].y = t0i - t2i;
    h[t + 2].x = t1r - sgn * t3i; h[t + 2].y = t1i + sgn * t3r;
    h[t + 6].x = t1r + sgn * t3i; h[t + 6].y = t1i - sgn * t3r;
  }
}

// wave shfl reduce + tiny LDS combine. Caller provides a PRIVATE red buffer per call
// site, so no trailing barrier is needed (single sync per reduction).
__device__ __forceinline__ void block_reduce2(float& pr, float& pi,
                                              float* redr, float* redi, int tid) {
  for (int off = 32; off > 0; off >>= 1) {
    pr += __shfl_down(pr, off, 64);
    pi += __shfl_down(pi, off, 64);
  }
  if ((tid & 63) == 0) { redr[tid >> 6] = pr; redi[tid >> 6] = pi; }
  __syncthreads();
  pr = redr[0] + redr[1] + redr[2] + redr[3];
  pi = redi[0] + redi[1] + redi[2] + redi[3];
}

// omode: 0 interleaved, 1 planar, 2 real-only. invN folded at the permute step.
// Pipeline: 11 barriers, 9R+9W LDS rounds. Requires >=64 VGPRs (launch_bounds 256,4)
// or the register-held state (hreg, cc/ss) spills to scratch.
#define ROW_PIPELINE(UP)                                                        \
  float2 hreg[8];                                                               \
  {                                                                             \
    float2 v[8];                                                                \
    _Pragma("unroll") for (int e = 0; e < 8; ++e) {                             \
      int k = tid + (e << 8);                                                   \
      float sv, cv; __sincosf(UP(e, 0), &sv, &cv);                              \
      float hr = hxr[(size_t)b * HID + k];                                      \
      float hi = hxi[(size_t)b * HID + k];                                      \
      v[e].x = cv * hr - sv * hi; v[e].y = cv * hi + sv * hr;                   \
    }                                                                           \
    fft_head(v, sA, tid, -1.f);                                                 \
  }                                                                             \
  __syncthreads();                                                              \
  fft_mid<8>(sA, sB, tid, -1.f);   __syncthreads();                             \
  fft_mid<32>(sB, sA, tid, -1.f);  __syncthreads();                             \
  fft_mid<128>(sA, sB, tid, -1.f); __syncthreads();                             \
  fft_tail(sB, hreg, tid, -1.f);                                                \
  float cc[8], ss[8];                                                           \
  {                                                                             \
    float pr = 0.f, pi = 0.f;                                                   \
    _Pragma("unroll") for (int e = 0; e < 8; ++e) {                             \
      float sv, cv; __sincosf(UP(e, 3), &sv, &cv);                              \
      cc[e] = cv; ss[e] = sv;                                                   \
      pr += cv * hreg[e].x + sv * hreg[e].y;                                    \
      pi += cv * hreg[e].y - sv * hreg[e].x;                                    \
    }                                                                           \
    block_reduce2(pr, pi, redr, redi, tid);                                     \
    _Pragma("unroll") for (int e = 0; e < 8; ++e) {                             \
      int k = tid + (e << 8);                                                   \
      h2st(sA, k, hreg[e].x - 2.f * (cc[e] * pr - ss[e] * pi),                  \
                  hreg[e].y - 2.f * (cc[e] * pi + ss[e] * pr));                 \
    }                                                                           \
  }                                                                             \
  __syncthreads();                                                              \
  {                                                                             \
    const float invN = 1.0f / (float)HID;                                       \
    float2 v[8];                                                                \
    _Pragma("unroll") for (int e = 0; e < 8; ++e) {                             \
      int k = tid + (e << 8);                                                   \
      float sv, cv; __sincosf(UP(e, 1), &sv, &cv);                              \
      float2 hh = h2ld(sA, perm[k]);                                            \
      v[e].x = (cv * hh.x - sv * hh.y) * invN;                                  \
      v[e].y = (cv * hh.y + sv * hh.x) * invN;                                  \
    }                                                                           \
    fft_head(v, sB, tid, 1.f);                                                  \
  }                                                                             \
  __syncthreads();                                                              \
  fft_mid<8>(sB, sA, tid, 1.f);   __syncthreads();                              \
  fft_mid<32>(sA, sB, tid, 1.f);  __syncthreads();                              \
  fft_mid<128>(sB, sA, tid, 1.f); __syncthreads();                              \
  fft_tail(sA, hreg, tid, 1.f);                                                 \
  float prj_r, prj_i;                                                           \
  {                                                                             \
    float pr = 0.f, pi = 0.f;                                                   \
    _Pragma("unroll") for (int e = 0; e < 8; ++e) {                             \
      float sv, cv; __sincosf(UP(e, 4), &sv, &cv);                              \
      cc[e] = cv; ss[e] = sv;                                                   \
      pr += cv * hreg[e].x + sv * hreg[e].y;                                    \
      pi += cv * hreg[e].y - sv * hreg[e].x;                                    \
    }                                                                           \
    block_reduce2(pr, pi, redr + 4, redi + 4, tid);                             \
    prj_r = pr; prj_i = pi;                                                     \
  }                                                                             \
  _Pragma("unroll") for (int e = 0; e < 8; ++e) {                               \
    int k = tid + (e << 8);                                                     \
    float hr = hreg[e].x - 2.f * (cc[e] * prj_r - ss[e] * prj_i);               \
    float hi = hreg[e].y - 2.f * (cc[e] * prj_i + ss[e] * prj_r);               \
    float s3, c3; __sincosf(UP(e, 2), &s3, &c3);                                \
    float zr = c3 * hr - s3 * hi;                                               \
    float zi = c3 * hi + s3 * hr;                                               \
    float mag = sqrtf(zr * zr + zi * zi);                                       \
    float nm = mag + beta[k];                                                   \
    nm = nm > 0.f ? nm : 0.f;                                                   \
    float orr, oii;                                                             \
    if (mag > 0.f) { float sc = nm / mag; orr = zr * sc; oii = zi * sc; }       \
    else { orr = nm; oii = 0.f; }                                               \
    long m = (long)b * HID + k;                                                 \
    if (omode == 1) {                                                           \
      const long half = (long)BATCH * HID;                                      \
      if (half + m < out_size_l) { out[m] = orr; out[half + m] = oii; }         \
    } else if (omode == 0) {                                                    \
      if (2 * m + 1 < out_size_l) {                                             \
        float2 o; o.x = orr; o.y = oii;                                         \
        *(float2*)(out + 2 * m) = o;                                            \
      }                                                                         \
    } else {                                                                    \
      if (m < out_size_l) out[m] = orr;                                         \
    }                                                                           \
  }

// ---------------- row kernel ----------------
// launch_bounds(256,4): 64 VGPRs/wave (4 blocks/CU). At (256,8) the allocator is
// capped at 32 VGPRs and the register-fused pipeline spills to scratch (R1 lesson:
// VGPR_Count stayed 32, FETCH/WRITE grew ~8MB of spill traffic, win shrank 15->5us).
__global__ __launch_bounds__(256, 4) void urnn_row(const _Float16* __restrict__ up16,
                                                   const float* __restrict__ hxr,
                                                   const float* __restrict__ hxi,
                                                   const float* __restrict__ beta,
                                                   const int* __restrict__ perm,
                                                   float* __restrict__ out,
                                                   int row0, long out_size_l, int omode) {
  __shared__ __half2 sA[HID], sB[HID];
  __shared__ float redr[8], redi[8];

  int tid = threadIdx.x;
  int b = row0 + blockIdx.x;
  const _Float16* uprow = up16 + (size_t)blockIdx.x * FIVEH;
#define UPG(e, s) ((float)uprow[(s) * HID + tid + ((e) << 8)])
  ROW_PIPELINE(UPG)
#undef UPG
}

// ---------------- ws-free fused fallback (f32-exact per-thread GEMM) ------------------
__global__ __launch_bounds__(256) void urnn_fused(const float* __restrict__ A,
                                                  const float* __restrict__ W,
                                                  const float* __restrict__ bias,
                                                  const float* __restrict__ hxr,
                                                  const float* __restrict__ hxi,
                                                  const float* __restrict__ beta,
                                                  const int* __restrict__ perm,
                                                  float* __restrict__ out,
                                                  long out_size_l, int omode) {
  __shared__ __half2 sA[HID], sB[HID];
  __shared__ float redr[8], redi[8];
  __shared__ float4 xs4[INP / 4];

  int tid = threadIdx.x;
  int b = blockIdx.x;

  if (tid < INP / 4) xs4[tid] = ((const float4*)(A + (size_t)b * INP))[tid];
  __syncthreads();

  float upreg[40];
#pragma unroll
  for (int se = 0; se < 40; ++se) {
    int n = ((se >> 3) << 11) + ((se & 7) << 8) + tid;
    upreg[se] = bias[n];
  }
  for (int kb = 0; kb < 4; ++kb) {
    float4 xv[8];
#pragma unroll
    for (int j = 0; j < 8; ++j) xv[j] = xs4[kb * 8 + j];
#pragma unroll
    for (int se = 0; se < 40; ++se) {
      int n = ((se >> 3) << 11) + ((se & 7) << 8) + tid;
      const float4* wr = (const float4*)(W + (size_t)n * INP + (kb << 5));
      float a = 0.f;
#pragma unroll
      for (int j = 0; j < 8; ++j) {
        float4 wv = wr[j];
        a += xv[j].x * wv.x + xv[j].y * wv.y + xv[j].z * wv.z + xv[j].w * wv.w;
      }
      upreg[se] += a;
    }
  }
#define UPR(e, s) (upreg[(s) * 8 + (e)])
  ROW_PIPELINE(UPR)
#undef UPR
}

extern "C" void kernel_launch(void* const* d_in, const int* in_sizes, int n_in,
                              void* d_out, int out_size, void* d_ws, size_t ws_size,
                              hipStream_t stream) {
  const float* input   = (const float*)d_in[0];
  const float* hx_real = (const float*)d_in[1];
  const float* hx_imag = (const float*)d_in[2];
  const float* W       = (const float*)d_in[3];
  const float* bvec    = (const float*)d_in[4];
  const float* beta    = (const float*)d_in[5];
  const int*   perm    = (const int*)d_in[6];

  int omode;
  if (out_size == BATCH * HID) omode = 2;
  else if (out_size == 2 * BATCH * HID) omode = 1;
  else omode = 0;

  const size_t rowbytes = (size_t)FIVEH * sizeof(_Float16);
  long chunk = (long)(ws_size / rowbytes);
  if (chunk > BATCH) chunk = BATCH;
  chunk &= ~127L;

  if (chunk >= 128) {
    _Float16* up16 = (_Float16*)d_ws;
    for (long row0 = 0; row0 < BATCH; row0 += chunk) {
      int rows = (int)((row0 + chunk <= BATCH) ? chunk : (BATCH - row0));
      dim3 g(FIVEH / 128, rows / 128);
      gemm_up<<<g, 256, 0, stream>>>(input, W, bvec, up16, (int)row0, rows);
      urnn_row<<<rows, 256, 0, stream>>>(up16, hx_real, hx_imag, beta, perm,
                                         (float*)d_out, (int)row0, (long)out_size, omode);
    }
  } else {
    urnn_fused<<<BATCH, 256, 0, stream>>>(input, W, bvec, hx_real, hx_imag, beta, perm,
                                          (float*)d_out, (long)out_size, omode);
  }
}